// Round 5
// baseline (862.631 us; speedup 1.0000x reference)
//
#include <hip/hip_runtime.h>

#define T_STEPS 512
#define BATCH   256

typedef _Float16 f16;
typedef unsigned long long u64;
typedef unsigned int u32;
typedef __attribute__((ext_vector_type(8))) _Float16 f16x8;
typedef __attribute__((ext_vector_type(4))) _Float16 f16x4;
typedef __attribute__((ext_vector_type(4))) float    f32x4;

#define L2E 1.44269504088896340736f

__device__ __forceinline__ float rcp_f(float x)  { return __builtin_amdgcn_rcpf(x); }
__device__ __forceinline__ float exp2_f(float x) { return __builtin_amdgcn_exp2f(x); }

// tanh in exp2 domain: tanh(x) = 1 - 2/(exp2(2*log2e*x)+1)
__device__ __forceinline__ float tanh_n(float x) {
    return fmaf(-2.0f, rcp_f(1.0f + exp2_f(2.0f * L2E * x)), 1.0f);
}
// tanh on 4 packed f16 (bottleneck tanh, applied on the h2 panel path)
__device__ __forceinline__ u64 tanh4_f16(u64 v) {
    f16x4 h = __builtin_bit_cast(f16x4, v);
    f16x4 r;
#pragma unroll
    for (int i = 0; i < 4; ++i) r[i] = (f16)tanh_n((float)h[i]);
    return __builtin_bit_cast(u64, r);
}

// Per-step barrier: LDS visibility only (global ops NOT drained).
// EVERY wave of a block must execute the SAME number of these per phase —
// round-3 regression was a preloop barrier executed by only some waves.
__device__ __forceinline__ void barrier_lgkm() {
    asm volatile("s_waitcnt lgkmcnt(0)\n\ts_barrier" ::: "memory");
}
// Counted drain: leave the 2 newest vmem ops in flight (per-wave in-order
// retirement) so the wait never blocks on a freshly issued store.
__device__ __forceinline__ void wait_vm2() {
    asm volatile("s_waitcnt vmcnt(2)" ::: "memory");
}
__device__ __forceinline__ void wait_vm0() {
    asm volatile("s_waitcnt vmcnt(0)" ::: "memory");
}

// Agent-scope relaxed atomics -> sc1 ops, coherent at L3 across XCDs.
__device__ __forceinline__ int  flag_load(const int* p) {
    return __hip_atomic_load(p, __ATOMIC_RELAXED, __HIP_MEMORY_SCOPE_AGENT);
}
__device__ __forceinline__ void flag_store(int* p, int v) {
    __hip_atomic_store(p, v, __ATOMIC_RELAXED, __HIP_MEMORY_SCOPE_AGENT);
}
__device__ __forceinline__ u64  panel_load(const u64* p) {
    return __hip_atomic_load(p, __ATOMIC_RELAXED, __HIP_MEMORY_SCOPE_AGENT);
}
__device__ __forceinline__ void panel_store(u64* p, u64 v) {
    __hip_atomic_store(p, v, __ATOMIC_RELAXED, __HIP_MEMORY_SCOPE_AGENT);
}
// vmcnt drains are PER-WAVE: each publisher wave owns a flag slot and only
// asserts ITS stores. Consumers take min of both slots (same 128B line).
__device__ __forceinline__ int flag_min2(const int* p) {
    const int a = flag_load(p), b = flag_load(p + 1);
    return a < b ? a : b;
}

// Persistent per-wave LSTM state for one 16-col u-tile (all 4 gates).
// Weights scaled by log2e (gates i,f,o) and 2*log2e (gate g); cell state in
// the 2*log2e domain; merged-rcp gate forms (8 trans per acc row).
template <int IN_DIM, int H>
struct Lstm {
    static constexpr int KTX = IN_DIM / 32, KTH = H / 32, KT = KTX + KTH;
    f16x8 bw[4][KT];
    float bias[4];
    float cst[4];
    int u, q;

    __device__ __forceinline__ void init(const float* __restrict__ w_ih,
                                         const float* __restrict__ w_hh,
                                         const float* __restrict__ b_ih,
                                         const float* __restrict__ b_hh,
                                         int unit, int lane) {
        q = lane >> 4;
        u = unit * 16 + (lane & 15);
#pragma unroll
        for (int g = 0; g < 4; ++g) {
            const float sc = (g == 2) ? 2.0f * L2E : L2E;
            const int row = g * H + u;
#pragma unroll
            for (int kt = 0; kt < KTX; ++kt) {
                const float* p = w_ih + (size_t)row * IN_DIM + kt * 32 + q * 8;
                f16x8 v;
#pragma unroll
                for (int j = 0; j < 8; ++j) v[j] = (f16)(p[j] * sc);
                bw[g][kt] = v;
            }
#pragma unroll
            for (int kt = 0; kt < KTH; ++kt) {
                const float* p = w_hh + (size_t)row * H + kt * 32 + q * 8;
                f16x8 v;
#pragma unroll
                for (int j = 0; j < 8; ++j) v[j] = (f16)(p[j] * sc);
                bw[g][KTX + kt] = v;
            }
            bias[g] = (b_ih[g * H + u] + b_hh[g * H + u]) * sc;
            cst[g] = 0.f;
        }
    }

    __device__ __forceinline__ void acc_init(f32x4 acc[4]) const {
#pragma unroll
        for (int g = 0; g < 4; ++g)
            acc[g] = (f32x4){bias[g], bias[g], bias[g], bias[g]};
    }
    __device__ __forceinline__ void mfma_kt(f32x4 acc[4], f16x8 a, int kt) const {
#pragma unroll
        for (int g = 0; g < 4; ++g)
            acc[g] = __builtin_amdgcn_mfma_f32_16x16x32_f16(a, bw[g][kt], acc[g], 0, 0, 0);
    }
    // input-projection MFMAs from an LDS row (KTX k-blocks)
    __device__ __forceinline__ void mfma_in(f32x4 acc[4], const f16* in_row) const {
#pragma unroll
        for (int kt = 0; kt < KTX; ++kt) {
            f16x8 a = *reinterpret_cast<const f16x8*>(in_row + kt * 32 + q * 8);
            mfma_kt(acc, a, kt);
        }
    }
    // recurrence MFMAs from an LDS row (KTH k-blocks) — the critical chain
    __device__ __forceinline__ void mfma_rec(f32x4 acc[4], const f16* rec_row) const {
#pragma unroll
        for (int kt = 0; kt < KTH; ++kt) {
            f16x8 a = *reinterpret_cast<const f16x8*>(rec_row + kt * 32 + q * 8);
            mfma_kt(acc, a, KTX + kt);
        }
    }
    __device__ __forceinline__ void gates(f32x4 acc[4], f16* hdst, int hp, float hold[4]) {
#pragma unroll
        for (int r = 0; r < 4; ++r) {
            const float yi = acc[0][r], yf = acc[1][r], yg = acc[2][r], yo = acc[3][r];
            const float Ei = exp2_f(-yi);
            const float G  = exp2_f(yg);                 // e^{2g}
            const float Ef = exp2_f(-yf);
            const float sf = rcp_f(1.0f + Ef);
            const float itg = (2.0f * L2E) * (G - 1.0f) *
                              rcp_f((1.0f + Ei) * (G + 1.0f));   // si * 2L2E*tanh(g)
            cst[r] = fmaf(sf, cst[r], itg);              // c' in 2L2E domain
            const float C  = exp2_f(cst[r]);             // e^{2c'}
            const float Eo = exp2_f(-yo);
            const float h  = (C - 1.0f) * rcp_f((1.0f + Eo) * (C + 1.0f)); // so*tanh(c')
            hdst[(4 * q + r) * hp + u] = (f16)h;
            hold[r] = h;
        }
    }
};

// X pre-convert: f32 [T,B,64] -> f16 [T,B,64], fully parallel.
__global__ __launch_bounds__(256)
void cvt_x(const float* __restrict__ X, f16* __restrict__ xh) {
    const size_t i = ((size_t)blockIdx.x * 256 + threadIdx.x) * 8;
    const f32x4 a = *reinterpret_cast<const f32x4*>(X + i);
    const f32x4 b = *reinterpret_cast<const f32x4*>(X + i + 4);
    f16x8 o;
    o[0] = (f16)a[0]; o[1] = (f16)a[1]; o[2] = (f16)a[2]; o[3] = (f16)a[3];
    o[4] = (f16)b[0]; o[5] = (f16)b[1]; o[6] = (f16)b[2]; o[7] = (f16)b[3];
    *reinterpret_cast<f16x8*>(xh + i) = o;
}

// Pair-fused pipeline, v3 (barrier-count-fixed, dual-slot flags):
//  blocks 0..15 (A): L1 (64->128, waves 0-7, self-loaded x from xh with 2-step
//   register prefetch, x-projection MFMAs OFF the critical path via double
//   accumulators) + L2 (128->32, waves 8-9, compute only) + PUB (waves 10-11:
//   tanh + sc1 panel store + counted drains + per-wave flag slot).
//  blocks 16..31 (B): L3 (32->128, waves 0-7, self-loaded h2t panels 2-deep,
//   min-of-slots flag polling, x-MFMA off-path) + L4 (128->64, waves 8-11,
//   delayed fp32 out stores).
// Parity rule: layer writes h(t) at parity t&1, reads recurrence at (t&1)^1.
// EVERY role executes exactly: init, 1 preloop barrier, 514 loop barriers.
__global__ __launch_bounds__(768, 3)
void lstm_fused(const f16* __restrict__ xh,
                const float* __restrict__ w1_ih, const float* __restrict__ w1_hh,
                const float* __restrict__ b1_ih, const float* __restrict__ b1_hh,
                const float* __restrict__ w2_ih, const float* __restrict__ w2_hh,
                const float* __restrict__ b2_ih, const float* __restrict__ b2_hh,
                const float* __restrict__ w3_ih, const float* __restrict__ w3_hh,
                const float* __restrict__ b3_ih, const float* __restrict__ b3_hh,
                const float* __restrict__ w4_ih, const float* __restrict__ w4_hh,
                const float* __restrict__ b4_ih, const float* __restrict__ b4_hh,
                f16* __restrict__ h2t, int* __restrict__ flags,
                float* __restrict__ out)
{
    __shared__ __attribute__((aligned(16))) char sm[16384];
    const int b = blockIdx.x, tid = threadIdx.x;
    const int wave = tid >> 6, lane = tid & 63;
    const int col = lane & 15, q = lane >> 4;

    if (b < 16) {
        // ================= block A: L1 + L2 + PUB =================
        const int g = b, bblk = g * 16;
        int* out_flag = flags + g * 32;
        constexpr int HP1 = 136, HP2 = 40;
        constexpr int H1_P = 16 * HP1, H2_P = 16 * HP2;
        f16* h1  = (f16*)sm;                  // [2][16][136]  8704 B
        f16* h2r = (f16*)(sm + 8704);         // [2][16][40]   2560 B

        for (int i = tid; i < (2 * H1_P + 2 * H2_P) / 2; i += 768)
            ((u32*)h1)[i] = 0u;

        if (wave < 8) {
            // ---- L1: 64 -> 128, t = s ----
            Lstm<64, 128> L;
            L.init(w1_ih, w1_hh, b1_ih, b1_hh, wave, lane);
            float hd[4];
            const size_t xstep = (size_t)BATCH * 64;
            const f16* xg = xh + (size_t)(bblk + col) * 64 + q * 8;
            f32x4 accA[4], accB[4];
            f16x8 xfE[2], xfO[2];      // input frags for even/odd step consume
            // preloop: acc(0) = bias + Wx*x(0); prefetch x(1),x(2)
            {
                f16x8 t0 = *reinterpret_cast<const f16x8*>(xg);
                f16x8 t1 = *reinterpret_cast<const f16x8*>(xg + 32);
                L.acc_init(accA);
                L.mfma_kt(accA, t0, 0);
                L.mfma_kt(accA, t1, 1);
                xfO[0] = *reinterpret_cast<const f16x8*>(xg + 1 * xstep);
                xfO[1] = *reinterpret_cast<const f16x8*>(xg + 1 * xstep + 32);
                xfE[0] = *reinterpret_cast<const f16x8*>(xg + 2 * xstep);
                xfE[1] = *reinterpret_cast<const f16x8*>(xg + 2 * xstep + 32);
            }
            barrier_lgkm();   // preloop barrier (all roles execute exactly one)
            auto sub = [&](int par, int s, f32x4 accCur[4], f32x4 accNext[4],
                           f16x8 xf[2]) {
                if (s < 512) {
                    __builtin_amdgcn_s_setprio(1);
                    L.mfma_rec(accCur, h1 + (par ^ 1) * H1_P + col * HP1);
                    L.gates(accCur, h1 + par * H1_P, HP1, hd);
                    __builtin_amdgcn_s_setprio(0);
                    // off-path: build acc(s+1) from x(s+1); refill with x(s+3)
                    L.acc_init(accNext);
                    L.mfma_kt(accNext, xf[0], 0);
                    L.mfma_kt(accNext, xf[1], 1);
                    if (s + 3 < 512) {
                        const f16* p = xg + (size_t)(s + 3) * xstep;
                        xf[0] = *reinterpret_cast<const f16x8*>(p);
                        xf[1] = *reinterpret_cast<const f16x8*>(p + 32);
                    }
                }
                barrier_lgkm();
            };
            for (int ss = 0; ss < 514; ss += 2) {
                sub(0, ss,     accA, accB, xfO);   // consume x(ss+1) (odd)
                sub(1, ss + 1, accB, accA, xfE);   // consume x(ss+2) (even)
            }
        } else if (wave < 10) {
            // ---- L2: 128 -> 32, t2 = s-1, compute only ----
            Lstm<128, 32> L;
            L.init(w2_ih, w2_hh, b2_ih, b2_hh, wave - 8, lane);
            float hd[4];
            barrier_lgkm();   // preloop barrier
            auto sub = [&](int par, int s) {
                if (s >= 1 && s <= 512) {
                    __builtin_amdgcn_s_setprio(1);
                    f32x4 acc[4];
                    L.acc_init(acc);
                    L.mfma_in(acc, h1 + (par ^ 1) * H1_P + col * HP1);  // h1(s-1)
                    L.mfma_rec(acc, h2r + par * H2_P + col * HP2);      // h2(s-2)
                    L.gates(acc, h2r + (par ^ 1) * H2_P, HP2, hd);      // h2(s-1)
                    __builtin_amdgcn_s_setprio(0);
                }
                barrier_lgkm();
            };
            for (int ss = 0; ss < 514; ss += 2) { sub(0, ss); sub(1, ss + 1); }
        } else {
            // ---- PUB: tanh'd h2 panels -> global, drains, per-wave flag ----
            const int pb = tid - 640, prow = pb >> 3, poff = pb & 7;
            int* slot = out_flag + (pb >> 6);              // wave10 -> 0, wave11 -> 1
            const u64* pl0 = (const u64*)(h2r + prow * HP2 + poff * 4);
            const u64* pl1 = (const u64*)(h2r + H2_P + prow * HP2 + poff * 4);
            u64* opg = (u64*)(h2t + (size_t)(bblk + prow) * 32) + poff;
            constexpr size_t pstep = (size_t)BATCH * 32 / 4;
            barrier_lgkm();   // preloop barrier
            auto sub = [&](int par, int s, const u64* src) {
                if (s >= 2 && s <= 513) {
                    const int p = s - 2;                   // panel index, p&1==par
                    panel_store(opg + (size_t)p * pstep, tanh4_f16(*src));
                    if (s >= 6 && (s & 3) == 2) {
                        wait_vm2();                        // own panels <= s-4 done
                        if ((pb & 63) == 0) flag_store(slot, s - 3);
                    }
                }
                barrier_lgkm();
            };
            for (int ss = 0; ss < 514; ss += 2) { sub(0, ss, pl0); sub(1, ss + 1, pl1); }
            // tail: drain OWN panel stores, publish own "all visible" slot
            wait_vm0();
            if ((pb & 63) == 0) flag_store(slot, 1 << 20);
        }
    } else {
        // ================= block B: L3 + L4 =================
        const int g = b - 16, bblk = g * 16;
        const int* in_flag = flags + g * 32;
        constexpr int HP3 = 136, HP4 = 72;
        constexpr int H3_P = 16 * HP3, H4_P = 16 * HP4;
        f16* h3 = (f16*)sm;                   // [2][16][136]  8704 B
        f16* h4 = (f16*)(sm + 8704);          // [2][16][72]   4608 B

        for (int i = tid; i < (2 * H3_P + 2 * H4_P) / 2; i += 768)
            ((u32*)h3)[i] = 0u;

        if (wave < 8) {
            // ---- L3: 32 -> 128, t = s; self-loaded h2t panels (per-wave) ----
            Lstm<32, 128> L;
            L.init(w3_ih, w3_hh, b3_ih, b3_hh, wave, lane);
            float hd[4];
            const u64* pg = (const u64*)h2t + (size_t)(bblk + col) * 8 + q * 2;
            constexpr size_t pstep = (size_t)BATCH * 8;    // u64s per panel
            f32x4 accA[4], accB[4];
            u64 xE[2], xO[2];
            int fl = -1, flp = -1;
            {
                do { fl = flag_min2(in_flag); } while (fl < 1);
                u64 t0 = panel_load(pg), t1 = panel_load(pg + 1);   // panel 0
                u64 pk[2] = {t0, t1};
                L.acc_init(accA);
                L.mfma_kt(accA, *reinterpret_cast<const f16x8*>(pk), 0);
                while (fl < 2) fl = flag_min2(in_flag);
                xO[0] = panel_load(pg + 1 * pstep);                 // panel 1
                xO[1] = panel_load(pg + 1 * pstep + 1);
                while (fl < 3) fl = flag_min2(in_flag);
                xE[0] = panel_load(pg + 2 * pstep);                 // panel 2
                xE[1] = panel_load(pg + 2 * pstep + 1);
                flp = flag_min2(in_flag);
            }
            barrier_lgkm();   // preloop barrier
            auto sub = [&](int par, int t, f32x4 accCur[4], f32x4 accNext[4],
                           u64 xf[2]) {
                if (t < 512) {
                    __builtin_amdgcn_s_setprio(1);
                    L.mfma_rec(accCur, h3 + (par ^ 1) * H3_P + col * HP3);
                    L.gates(accCur, h3 + par * H3_P, HP3, hd);
                    __builtin_amdgcn_s_setprio(0);
                    // off-path: acc(t+1) from panel t+1; refill with panel t+3
                    L.acc_init(accNext);
                    u64 pk[2] = {xf[0], xf[1]};
                    L.mfma_kt(accNext, *reinterpret_cast<const f16x8*>(pk), 0);
                    if (t + 3 < 512) {
                        if (flp > fl) fl = flp;
                        while (fl < t + 4) fl = flag_min2(in_flag);
                        const u64* p = pg + (size_t)(t + 3) * pstep;
                        xf[0] = panel_load(p);
                        xf[1] = panel_load(p + 1);
                        flp = flag_min2(in_flag);   // consumed next step
                    }
                }
                barrier_lgkm();
            };
            for (int tt = 0; tt < 514; tt += 2) {
                sub(0, tt,     accA, accB, xO);
                sub(1, tt + 1, accB, accA, xE);
            }
        } else {
            // ---- L4: 128 -> 64, t4 = t-1, fp32 delayed out writes ----
            Lstm<128, 64> L;
            L.init(w4_ih, w4_hh, b4_ih, b4_hh, wave - 8, lane);
            float hold[4] = {0.f, 0.f, 0.f, 0.f};
            float* outp = out + ((size_t)bblk + 4 * q) * 64 + (wave - 8) * 16 + col;
            barrier_lgkm();   // preloop barrier
            auto sub = [&](int par, int t) {
                if (t >= 1 && t <= 512) {
                    if (t >= 2) {
#pragma unroll
                        for (int r = 0; r < 4; ++r) outp[r * 64] = hold[r]; // out(t-2)
                        outp += (size_t)BATCH * 64;
                    }
                    __builtin_amdgcn_s_setprio(1);
                    f32x4 acc[4];
                    L.acc_init(acc);
                    L.mfma_in(acc, h3 + (par ^ 1) * H3_P + col * HP3);  // h3(t-1)
                    L.mfma_rec(acc, h4 + par * H4_P + col * HP4);       // h4(t-2)
                    L.gates(acc, h4 + (par ^ 1) * H4_P, HP4, hold);     // h4(t-1)
                    __builtin_amdgcn_s_setprio(0);
                }
                barrier_lgkm();
            };
            for (int tt = 0; tt < 514; tt += 2) { sub(0, tt); sub(1, tt + 1); }
            // epilogue: out(511)
#pragma unroll
            for (int r = 0; r < 4; ++r) outp[r * 64] = hold[r];
        }
    }
}

extern "C" void kernel_launch(void* const* d_in, const int* in_sizes, int n_in,
                              void* d_out, int out_size, void* d_ws, size_t ws_size,
                              hipStream_t stream) {
    const float* X     = (const float*)d_in[0];
    const float* w1_ih = (const float*)d_in[1];
    const float* w1_hh = (const float*)d_in[2];
    const float* b1_ih = (const float*)d_in[3];
    const float* b1_hh = (const float*)d_in[4];
    const float* w2_ih = (const float*)d_in[5];
    const float* w2_hh = (const float*)d_in[6];
    const float* b2_ih = (const float*)d_in[7];
    const float* b2_hh = (const float*)d_in[8];
    const float* w3_ih = (const float*)d_in[9];
    const float* w3_hh = (const float*)d_in[10];
    const float* b3_ih = (const float*)d_in[11];
    const float* b3_hh = (const float*)d_in[12];
    const float* w4_ih = (const float*)d_in[13];
    const float* w4_hh = (const float*)d_in[14];
    const float* b4_ih = (const float*)d_in[15];
    const float* b4_hh = (const float*)d_in[16];

    float* out = (float*)d_out;

    // ws layout: flags 16 x (32 ints, one 128B line each) @ 0 (poison
    // 0xAAAAAAAA < 0 => "not ready"; slots 0 and 1 per group are the two
    // publisher-wave watermarks); h2t = tanh(h2) f16 [T,B,32] @ 4096 (8 MB);
    // xh = f16 X [T,B,64] after it (16 MB).
    int* flags = (int*)d_ws;
    f16* h2t = (f16*)((char*)d_ws + 4096);
    f16* xh  = (f16*)((char*)d_ws + 4096 + (size_t)T_STEPS * BATCH * 32 * 2);

    cvt_x<<<4096, 256, 0, stream>>>(X, xh);
    lstm_fused<<<32, 768, 0, stream>>>(xh,
        w1_ih, w1_hh, b1_ih, b1_hh, w2_ih, w2_hh, b2_ih, b2_hh,
        w3_ih, w3_hh, b3_ih, b3_hh, w4_ih, w4_hh, b4_ih, b4_hh,
        h2t, flags, out);
}

// Round 6
// 667.020 us; speedup vs baseline: 1.2933x; 1.2933x over previous
//
#include <hip/hip_runtime.h>

#define T_STEPS 512
#define BATCH   256

typedef _Float16 f16;
typedef unsigned long long u64;
typedef __attribute__((ext_vector_type(8))) _Float16 f16x8;
typedef __attribute__((ext_vector_type(4))) _Float16 f16x4;
typedef __attribute__((ext_vector_type(4))) float    f32x4;

#define L2E 1.44269504088896340736f

__device__ __forceinline__ float rcp_f(float x)  { return __builtin_amdgcn_rcpf(x); }
__device__ __forceinline__ float exp2_f(float x) { return __builtin_amdgcn_exp2f(x); }

// tanh in exp2 domain: tanh(x) = 1 - 2/(exp2(2*log2e*x)+1)
__device__ __forceinline__ float tanh_n(float x) {
    return fmaf(-2.0f, rcp_f(1.0f + exp2_f(2.0f * L2E * x)), 1.0f);
}
// tanh on 4 packed f16 (bottleneck tanh, applied on L2's panel store)
__device__ __forceinline__ u64 tanh4_f16(u64 v) {
    f16x4 h = __builtin_bit_cast(f16x4, v);
    f16x4 r;
#pragma unroll
    for (int i = 0; i < 4; ++i) r[i] = (f16)tanh_n((float)h[i]);
    return __builtin_bit_cast(u64, r);
}

// Per-step barrier: LDS visibility only (global ops NOT drained).
__device__ __forceinline__ void barrier_lgkm() {
    asm volatile("s_waitcnt lgkmcnt(0)\n\ts_barrier" ::: "memory");
}
// Signal-point barrier: drain all VMEM so panels are globally visible.
__device__ __forceinline__ void barrier_drain() {
    asm volatile("s_waitcnt vmcnt(0) lgkmcnt(0)\n\ts_barrier" ::: "memory");
}

// Agent-scope relaxed atomics -> sc1 ops, coherent at L3 across XCDs.
__device__ __forceinline__ int  flag_load(const int* p) {
    return __hip_atomic_load(p, __ATOMIC_RELAXED, __HIP_MEMORY_SCOPE_AGENT);
}
__device__ __forceinline__ void flag_store(int* p, int v) {
    __hip_atomic_store(p, v, __ATOMIC_RELAXED, __HIP_MEMORY_SCOPE_AGENT);
}
__device__ __forceinline__ u64  panel_load(const u64* p) {
    return __hip_atomic_load(p, __ATOMIC_RELAXED, __HIP_MEMORY_SCOPE_AGENT);
}
__device__ __forceinline__ void panel_store(u64* p, u64 v) {
    __hip_atomic_store(p, v, __ATOMIC_RELAXED, __HIP_MEMORY_SCOPE_AGENT);
}

// One LSTM layer over one 16-batch group (NT = 4H threads). MFMA structure
// verified rounds 2-6 of the prior session. Weights/biases are scaled by
// log2e (gates i,f,o) and 2*log2e (gate g) at load time; cell state kept in
// the 2*log2e domain so all nonlinearities are rcp(1+exp2(+/-y)) forms.
// This round (vs the 650us baseline): (1) input-proj and recurrence MFMAs
// accumulate into SEPARATE chains (accX bias-seeded, accH zero-seeded,
// summed at gate time) so the post-barrier dependent-MFMA depth drops from
// KTX+KTH to max(KTX,KTH); (2) merged-rcp gate forms (8 trans/row, one less
// serial trans level). Sync protocol is UNCHANGED from the proven baseline.
// Pipeline: flag f = "x panels 0..f-1 globally visible"; producer publishes
// f = t-1 at steps t%4==0 (after drain barrier at end of t-1); consumer at
// step tau prefetches x(tau+1) once flag >= tau+2.
template <int IN_DIM, int H, bool IN_F32, bool OUT_PANEL, bool OUT_TANH>
__device__ __forceinline__ void lstm_layer_dev(
    char* sm,
    const void* __restrict__ xv,       // IN_F32 ? f32 [T,B,IN] : f16 [T,B,IN]
    const int* in_flag,                // upstream flag (unused if IN_F32)
    int* out_flag,                     // our flag (unused if !OUT_PANEL)
    const float* __restrict__ w_ih, const float* __restrict__ w_hh,
    const float* __restrict__ b_ih, const float* __restrict__ b_hh,
    void* __restrict__ outv,           // OUT_PANEL ? f16 [T,B,H] : f32 [T,B,H]
    int group, int ltid)
{
    constexpr int KTX = IN_DIM / 32, KTH = H / 32, KT = KTX + KTH;
    constexpr int XP = IN_DIM + 8, HP = H + 8, NT = 4 * H;

    f16 (*xs)[16][XP] = (f16(*)[16][XP])sm;                       // [2][16][XP]
    f16 (*hs)[16][HP] = (f16(*)[16][HP])(sm + 2 * 16 * XP * 2);   // [2][16][HP]

    const int wave = ltid >> 6, lane = ltid & 63;
    const int col = lane & 15, q = lane >> 4;
    const int bblk = group * 16;
    const int u = wave * 16 + col;

    // ---- one-time: B-fragments (weights, log2e-scaled) -> registers ----
    f16x8 bw[4][KT];
#pragma unroll
    for (int g = 0; g < 4; ++g) {
        const float sc = (g == 2) ? 2.0f * L2E : L2E;
        const int row = g * H + u;
#pragma unroll
        for (int kt = 0; kt < KTX; ++kt) {
            const float* p = w_ih + (size_t)row * IN_DIM + kt * 32 + q * 8;
            f16x8 v;
#pragma unroll
            for (int j = 0; j < 8; ++j) v[j] = (f16)(p[j] * sc);
            bw[g][kt] = v;
        }
#pragma unroll
        for (int kt = 0; kt < KTH; ++kt) {
            const float* p = w_hh + (size_t)row * H + kt * 32 + q * 8;
            f16x8 v;
#pragma unroll
            for (int j = 0; j < 8; ++j) v[j] = (f16)(p[j] * sc);
            bw[g][KTX + kt] = v;
        }
    }
    float bias[4];
#pragma unroll
    for (int g = 0; g < 4; ++g)
        bias[g] = (b_ih[g * H + u] + b_hh[g * H + u]) * ((g == 2) ? 2.0f * L2E : L2E);
    float cst[4] = {0.f, 0.f, 0.f, 0.f};   // cell state, 2*log2e domain

    // ---- input staging: 16B chunks (4 f32 or 8 f16) ----
    constexpr int ELD = IN_F32 ? 4 : 8;
    constexpr int EPR = IN_DIM / ELD;
    constexpr int NCH = 16 * EPR;
    constexpr int CPT = (NCH + NT - 1) / NT;
    constexpr long XADVB = (long)BATCH * IN_DIM * (IN_F32 ? 4 : 2);
    bool sv[CPT]; const char* sgp[CPT]; f16* slp[CPT];
    constexpr int LDSD = 16 * XP;          // f16 elems between xs buffers
#pragma unroll
    for (int k = 0; k < CPT; ++k) {
        const int cc = ltid + k * NT;
        sv[k] = (cc < NCH);
        const int r_ = (cc < NCH ? cc : 0) / EPR;
        const int o_ = (cc < NCH ? cc : 0) % EPR;
        sgp[k] = (const char*)xv + ((size_t)(bblk + r_) * IN_DIM + o_ * ELD) * (IN_F32 ? 4 : 2);
        slp[k] = &xs[0][r_][o_ * ELD];
    }

    // ---- output setup ----
    constexpr int OEPR = H / 4;            // u64 chunks per row; NT == 16*OEPR
    u64* opg = nullptr;
    f16* olds = nullptr;
    float* outp_f32 = nullptr;
    if constexpr (OUT_PANEL) {
        const int orow = ltid / OEPR, ooff = ltid % OEPR;
        opg  = (u64*)((f16*)outv + (size_t)(bblk + orow) * H) + ooff;
        olds = &hs[0][orow][ooff * 4];
    } else {
        outp_f32 = (float*)outv + ((size_t)bblk + 4 * q) * H + u;
    }
    constexpr int HLDSD = 16 * HP;

    // ---- pre-loop: zero h(0); wait upstream; stage x(0) ----
    for (int i = ltid; i < 16 * HP; i += NT) hs[0][i / HP][i % HP] = (f16)0.f;
    int seen = 0;
    if constexpr (!IN_F32) {
        do { seen = flag_load(in_flag); } while (seen < 1);
    }
#pragma unroll
    for (int k = 0; k < CPT; ++k) {
        if (sv[k]) {
            if constexpr (IN_F32) {
                const f32x4 v = *reinterpret_cast<const f32x4*>(sgp[k]);
                f16x4 h4;
                h4[0] = (f16)v[0]; h4[1] = (f16)v[1]; h4[2] = (f16)v[2]; h4[3] = (f16)v[3];
                *reinterpret_cast<f16x4*>(slp[k]) = h4;
            } else {
                u64 a = panel_load((const u64*)sgp[k]);
                u64 b = panel_load((const u64*)sgp[k] + 1);
                u64 pk[2] = {a, b};
                *reinterpret_cast<f16x8*>(slp[k]) = *reinterpret_cast<const f16x8*>(pk);
            }
            sgp[k] += XADVB;
        }
    }
    barrier_drain();

    float hold[4] = {0.f, 0.f, 0.f, 0.f};

    // ---- one step; pbv/dodrain/dopub are literal at each call site ----
    auto step = [&](int t, int pbv, bool dodrain, bool dopub) {
        if constexpr (OUT_PANEL) {
            if (dopub && t >= 4 && ltid == 0) flag_store(out_flag, t - 1);
        }

        // prefetch x(t+1)
        f32x4 xr32[CPT]; u64 xr16[CPT][2];
        const bool pf = (t + 1 < T_STEPS);
        if (pf) {
            if constexpr (!IN_F32) {
                if (seen < t + 2) {
                    do { seen = flag_load(in_flag); } while (seen < t + 2);
                }
            }
#pragma unroll
            for (int k = 0; k < CPT; ++k) {
                if (sv[k]) {
                    if constexpr (IN_F32) {
                        xr32[k] = *reinterpret_cast<const f32x4*>(sgp[k]);
                    } else {
                        xr16[k][0] = panel_load((const u64*)sgp[k]);
                        xr16[k][1] = panel_load((const u64*)sgp[k] + 1);
                    }
                    sgp[k] += XADVB;
                }
            }
        }

        // write step t-1's output (h(t-1) sits in hs[pbv])
        if (t >= 1) {
            if constexpr (OUT_PANEL) {
                u64 v = *reinterpret_cast<const u64*>(olds + pbv * HLDSD);
                if constexpr (OUT_TANH) v = tanh4_f16(v);
                panel_store(opg, v);
                opg += (size_t)BATCH * H / 4;
            } else {
#pragma unroll
                for (int r = 0; r < 4; ++r) outp_f32[r * H] = hold[r];
                outp_f32 += (size_t)BATCH * H;
            }
        }

        // A-fragments
        f16x8 a[KT];
#pragma unroll
        for (int kt = 0; kt < KTX; ++kt)
            a[kt] = *reinterpret_cast<const f16x8*>(&xs[pbv][col][kt * 32 + q * 8]);
#pragma unroll
        for (int kt = 0; kt < KTH; ++kt)
            a[KTX + kt] = *reinterpret_cast<const f16x8*>(&hs[pbv][col][kt * 32 + q * 8]);

        // MFMA: input-proj and recurrence in SEPARATE accumulator chains
        // (depth max(KTX,KTH) instead of KTX+KTH), summed at gate time.
        f32x4 accX[4], accH[4];
#pragma unroll
        for (int g = 0; g < 4; ++g) {
            accX[g] = (f32x4){bias[g], bias[g], bias[g], bias[g]};
            accH[g] = (f32x4){0.f, 0.f, 0.f, 0.f};
        }
#pragma unroll
        for (int kt = 0; kt < KTX; ++kt)
#pragma unroll
            for (int g = 0; g < 4; ++g)
                accX[g] = __builtin_amdgcn_mfma_f32_16x16x32_f16(a[kt], bw[g][kt], accX[g], 0, 0, 0);
#pragma unroll
        for (int kt = 0; kt < KTH; ++kt)
#pragma unroll
            for (int g = 0; g < 4; ++g)
                accH[g] = __builtin_amdgcn_mfma_f32_16x16x32_f16(a[KTX + kt], bw[g][KTX + kt], accH[g], 0, 0, 0);

        // gates (exp2 domain), merged-rcp forms:
        // si*tanh(g)*2L2E = 2L2E*(G-1)/((1+Ei)(G+1)),  h = (C-1)/((1+Eo)(C+1))
#pragma unroll
        for (int r = 0; r < 4; ++r) {
            const float yi = accX[0][r] + accH[0][r];
            const float yf = accX[1][r] + accH[1][r];
            const float yg = accX[2][r] + accH[2][r];   // scaled by 2*log2e
            const float yo = accX[3][r] + accH[3][r];
            const float Ei = exp2_f(-yi);
            const float G  = exp2_f(yg);                 // e^{2g}
            const float Ef = exp2_f(-yf);
            const float sf = rcp_f(1.0f + Ef);
            const float itg = (2.0f * L2E) * (G - 1.0f) *
                              rcp_f((1.0f + Ei) * (G + 1.0f));   // si * 2L2E*tanh(g)
            cst[r] = fmaf(sf, cst[r], itg);              // c' = 2*log2e*c
            const float C  = exp2_f(cst[r]);             // e^{2c'}
            const float Eo = exp2_f(-yo);
            const float h  = (C - 1.0f) * rcp_f((1.0f + Eo) * (C + 1.0f)); // so*tanh(c')
            hs[pbv ^ 1][4 * q + r][u] = (f16)h;
            if constexpr (!OUT_PANEL) hold[r] = h;
        }

        // commit x(t+1) LAST (hides sc1 load latency under the step)
        if (pf) {
#pragma unroll
            for (int k = 0; k < CPT; ++k) {
                if (sv[k]) {
                    f16* dst = slp[k] + (pbv ^ 1) * LDSD;
                    if constexpr (IN_F32) {
                        f16x4 h4;
                        h4[0] = (f16)xr32[k][0]; h4[1] = (f16)xr32[k][1];
                        h4[2] = (f16)xr32[k][2]; h4[3] = (f16)xr32[k][3];
                        *reinterpret_cast<f16x4*>(dst) = h4;
                    } else {
                        *reinterpret_cast<f16x8*>(dst) =
                            *reinterpret_cast<const f16x8*>(xr16[k]);
                    }
                }
            }
        }

        // refresh 'seen' only on publish-cadence steps
        if constexpr (!IN_F32) {
            if (dopub && seen < t + 9) seen = flag_load(in_flag);
        }

        if (dodrain) barrier_drain(); else barrier_lgkm();
    };

    for (int tb = 0; tb < T_STEPS; tb += 4) {
        step(tb + 0, 0, false, true);
        step(tb + 1, 1, false, false);
        step(tb + 2, 0, false, false);
        step(tb + 3, 1, true,  false);
    }

    // ---- epilogue: final output (h(T-1) in hs[0]), drain, final flag ----
    if constexpr (OUT_PANEL) {
        u64 v = *reinterpret_cast<const u64*>(olds);
        if constexpr (OUT_TANH) v = tanh4_f16(v);
        panel_store(opg, v);
    } else {
#pragma unroll
        for (int r = 0; r < 4; ++r) outp_f32[r * H] = hold[r];
    }
    barrier_drain();
    if constexpr (OUT_PANEL) {
        if (ltid == 0) flag_store(out_flag, T_STEPS + 4);
    }
}

__global__ __launch_bounds__(512, 1)
void lstm_fused(const float* __restrict__ X,
                const float* __restrict__ w1_ih, const float* __restrict__ w1_hh,
                const float* __restrict__ b1_ih, const float* __restrict__ b1_hh,
                const float* __restrict__ w2_ih, const float* __restrict__ w2_hh,
                const float* __restrict__ b2_ih, const float* __restrict__ b2_hh,
                const float* __restrict__ w3_ih, const float* __restrict__ w3_hh,
                const float* __restrict__ b3_ih, const float* __restrict__ b3_hh,
                const float* __restrict__ w4_ih, const float* __restrict__ w4_hh,
                const float* __restrict__ b4_ih, const float* __restrict__ b4_hh,
                f16* __restrict__ h1, f16* __restrict__ h2, f16* __restrict__ h3,
                int* __restrict__ flags, float* __restrict__ out)
{
    __shared__ __attribute__((aligned(16))) char smem[45056];
    const int b = blockIdx.x, tid = threadIdx.x;

    if (b < 16) {
        // L1: 64 -> 128, fp32 in, panel out, 1 group/block (512 thr)
        lstm_layer_dev<64, 128, true, true, false>(
            smem, X, nullptr, flags + 0 * 16 + b,
            w1_ih, w1_hh, b1_ih, b1_hh, h1, b, tid);
    } else if (b < 20) {
        // L2: 128 -> 32, 4 groups/block (128 thr each); bottleneck tanh is
        // applied on the PANEL path only (recurrence h stays raw)
        const int gl = tid >> 7;
        const int g  = (b - 16) * 4 + gl;
        lstm_layer_dev<128, 32, false, true, true>(
            smem + gl * 11264, h1, flags + 0 * 16 + g, flags + 1 * 16 + g,
            w2_ih, w2_hh, b2_ih, b2_hh, h2, g, tid & 127);
    } else if (b < 36) {
        // L3: 32 -> 128; input panel h2 is already tanh'd
        const int g = b - 20;
        lstm_layer_dev<32, 128, false, true, false>(
            smem, h2, flags + 1 * 16 + g, flags + 2 * 16 + g,
            w3_ih, w3_hh, b3_ih, b3_hh, h3, g, tid);
    } else {
        // L4: 128 -> 64, 2 groups/block (256 thr each), fp32 final out
        const int gl = tid >> 8;
        const int g  = (b - 36) * 2 + gl;
        lstm_layer_dev<128, 64, false, false, false>(
            smem + gl * 13312, h3, flags + 2 * 16 + g, nullptr,
            w4_ih, w4_hh, b4_ih, b4_hh, out, g, tid & 255);
    }
}

extern "C" void kernel_launch(void* const* d_in, const int* in_sizes, int n_in,
                              void* d_out, int out_size, void* d_ws, size_t ws_size,
                              hipStream_t stream) {
    const float* X     = (const float*)d_in[0];
    const float* w1_ih = (const float*)d_in[1];
    const float* w1_hh = (const float*)d_in[2];
    const float* b1_ih = (const float*)d_in[3];
    const float* b1_hh = (const float*)d_in[4];
    const float* w2_ih = (const float*)d_in[5];
    const float* w2_hh = (const float*)d_in[6];
    const float* b2_ih = (const float*)d_in[7];
    const float* b2_hh = (const float*)d_in[8];
    const float* w3_ih = (const float*)d_in[9];
    const float* w3_hh = (const float*)d_in[10];
    const float* b3_ih = (const float*)d_in[11];
    const float* b3_hh = (const float*)d_in[12];
    const float* w4_ih = (const float*)d_in[13];
    const float* w4_hh = (const float*)d_in[14];
    const float* b4_ih = (const float*)d_in[15];
    const float* b4_hh = (const float*)d_in[16];

    float* out = (float*)d_out;

    // ws: flags[48] ints (poison 0xAAAAAAAA < 0 => "not ready"), then f16
    // panels h1 [T,B,128], h2 [T,B,32], h3 [T,B,128]
    int* flags = (int*)d_ws;
    f16* h1 = (f16*)((char*)d_ws + 256);
    f16* h2 = h1 + (size_t)T_STEPS * BATCH * 128;
    f16* h3 = h2 + (size_t)T_STEPS * BATCH * 32;

    lstm_fused<<<44, 512, 0, stream>>>(X,
        w1_ih, w1_hh, b1_ih, b1_hh, w2_ih, w2_hh, b2_ih, b2_hh,
        w3_ih, w3_hh, b3_ih, b3_hh, w4_ih, w4_hh, b4_ih, b4_hh,
        h1, h2, h3, flags, out);
}

// Round 7
// 634.277 us; speedup vs baseline: 1.3600x; 1.0516x over previous
//
#include <hip/hip_runtime.h>

#define T_STEPS 512
#define BATCH   256

typedef _Float16 f16;
typedef unsigned long long u64;
typedef __attribute__((ext_vector_type(8))) _Float16 f16x8;
typedef __attribute__((ext_vector_type(4))) _Float16 f16x4;
typedef __attribute__((ext_vector_type(4))) float    f32x4;

#define L2E 1.44269504088896340736f

__device__ __forceinline__ float rcp_f(float x)  { return __builtin_amdgcn_rcpf(x); }
__device__ __forceinline__ float exp2_f(float x) { return __builtin_amdgcn_exp2f(x); }

// tanh in exp2 domain: tanh(x) = 1 - 2/(exp2(2*log2e*x)+1)
__device__ __forceinline__ float tanh_n(float x) {
    return fmaf(-2.0f, rcp_f(1.0f + exp2_f(2.0f * L2E * x)), 1.0f);
}
// tanh on 4 packed f16 (bottleneck tanh, applied on L2's panel store)
__device__ __forceinline__ u64 tanh4_f16(u64 v) {
    f16x4 h = __builtin_bit_cast(f16x4, v);
    f16x4 r;
#pragma unroll
    for (int i = 0; i < 4; ++i) r[i] = (f16)tanh_n((float)h[i]);
    return __builtin_bit_cast(u64, r);
}

// Per-step barrier: LDS visibility only (global ops NOT drained).
__device__ __forceinline__ void barrier_lgkm() {
    asm volatile("s_waitcnt lgkmcnt(0)\n\ts_barrier" ::: "memory");
}
// Full drain barrier (pre/epilogue only).
__device__ __forceinline__ void barrier_drain() {
    asm volatile("s_waitcnt vmcnt(0) lgkmcnt(0)\n\ts_barrier" ::: "memory");
}
// Counted drain barrier: wait until <= K vmem ops outstanding. The K newest
// ops are this step's prefetch loads (issued AFTER all stores -> in-order
// vmcnt retirement guarantees every store is retired), so panel stores are
// globally visible without waiting on the fresh sc1 loads.
template <int K>
__device__ __forceinline__ void barrier_drain_k() {
    if constexpr (K == 1)
        asm volatile("s_waitcnt vmcnt(1) lgkmcnt(0)\n\ts_barrier" ::: "memory");
    else if constexpr (K == 2)
        asm volatile("s_waitcnt vmcnt(2) lgkmcnt(0)\n\ts_barrier" ::: "memory");
    else if constexpr (K == 4)
        asm volatile("s_waitcnt vmcnt(4) lgkmcnt(0)\n\ts_barrier" ::: "memory");
    else
        asm volatile("s_waitcnt vmcnt(0) lgkmcnt(0)\n\ts_barrier" ::: "memory");
}

// Agent-scope relaxed atomics -> sc1 ops, coherent at L3 across XCDs.
__device__ __forceinline__ int  flag_load(const int* p) {
    return __hip_atomic_load(p, __ATOMIC_RELAXED, __HIP_MEMORY_SCOPE_AGENT);
}
__device__ __forceinline__ void flag_store(int* p, int v) {
    __hip_atomic_store(p, v, __ATOMIC_RELAXED, __HIP_MEMORY_SCOPE_AGENT);
}
__device__ __forceinline__ u64  panel_load(const u64* p) {
    return __hip_atomic_load(p, __ATOMIC_RELAXED, __HIP_MEMORY_SCOPE_AGENT);
}
__device__ __forceinline__ void panel_store(u64* p, u64 v) {
    __hip_atomic_store(p, v, __ATOMIC_RELAXED, __HIP_MEMORY_SCOPE_AGENT);
}

// One LSTM layer over one 16-batch group (NT = 4H threads). MFMA structure
// verified rounds 2-6 (prior session). Weights/biases scaled by log2e (gates
// i,f,o) and 2*log2e (gate g) at load time; cell state kept in the 2*log2e
// domain; merged-rcp gate forms (8 trans/row, verified identical absmax).
//
// This round vs the 563us baseline (sync protocol unchanged):
//  (a) 2-step-deep register prefetch: step t COMMITS x(t+1) from regs loaded
//      at step t-1 (sc1 latency fully off the critical path) and ISSUES
//      x(t+2) into the alternate named reg set (no runtime indexing).
//      Consumer poll requirement becomes flag >= t+3 (skew only).
//  (b) output panel store is issued BEFORE the prefetch loads, so the
//      every-4th-step drain uses a counted vmcnt(NLOAD) that drains all
//      stores but not this step's loads.
// Pipeline: flag f = "x panels 0..f-1 globally visible"; producer publishes
// f = t-1 at steps t%4==0 (after drain at end of t-1).
template <int IN_DIM, int H, bool IN_F32, bool OUT_PANEL, bool OUT_TANH>
__device__ __forceinline__ void lstm_layer_dev(
    char* sm,
    const void* __restrict__ xv,       // IN_F32 ? f32 [T,B,IN] : f16 [T,B,IN]
    const int* in_flag,                // upstream flag (unused if IN_F32)
    int* out_flag,                     // our flag (unused if !OUT_PANEL)
    const float* __restrict__ w_ih, const float* __restrict__ w_hh,
    const float* __restrict__ b_ih, const float* __restrict__ b_hh,
    void* __restrict__ outv,           // OUT_PANEL ? f16 [T,B,H] : f32 [T,B,H]
    int group, int ltid)
{
    constexpr int KTX = IN_DIM / 32, KTH = H / 32, KT = KTX + KTH;
    constexpr int XP = IN_DIM + 8, HP = H + 8, NT = 4 * H;

    f16 (*xs)[16][XP] = (f16(*)[16][XP])sm;                       // [2][16][XP]
    f16 (*hs)[16][HP] = (f16(*)[16][HP])(sm + 2 * 16 * XP * 2);   // [2][16][HP]

    const int wave = ltid >> 6, lane = ltid & 63;
    const int col = lane & 15, q = lane >> 4;
    const int bblk = group * 16;
    const int u = wave * 16 + col;

    // ---- one-time: B-fragments (weights, log2e-scaled) -> registers ----
    f16x8 bw[4][KT];
#pragma unroll
    for (int g = 0; g < 4; ++g) {
        const float sc = (g == 2) ? 2.0f * L2E : L2E;
        const int row = g * H + u;
#pragma unroll
        for (int kt = 0; kt < KTX; ++kt) {
            const float* p = w_ih + (size_t)row * IN_DIM + kt * 32 + q * 8;
            f16x8 v;
#pragma unroll
            for (int j = 0; j < 8; ++j) v[j] = (f16)(p[j] * sc);
            bw[g][kt] = v;
        }
#pragma unroll
        for (int kt = 0; kt < KTH; ++kt) {
            const float* p = w_hh + (size_t)row * H + kt * 32 + q * 8;
            f16x8 v;
#pragma unroll
            for (int j = 0; j < 8; ++j) v[j] = (f16)(p[j] * sc);
            bw[g][KTX + kt] = v;
        }
    }
    float bias[4];
#pragma unroll
    for (int g = 0; g < 4; ++g)
        bias[g] = (b_ih[g * H + u] + b_hh[g * H + u]) * ((g == 2) ? 2.0f * L2E : L2E);
    float cst[4] = {0.f, 0.f, 0.f, 0.f};   // cell state, 2*log2e domain

    // ---- input staging: 16B chunks (4 f32 or 8 f16) ----
    constexpr int ELD = IN_F32 ? 4 : 8;
    constexpr int EPR = IN_DIM / ELD;
    constexpr int NCH = 16 * EPR;
    constexpr int CPT = (NCH + NT - 1) / NT;
    constexpr int NLOAD = IN_F32 ? CPT : 2 * CPT;   // load instrs per step
    constexpr long XADVB = (long)BATCH * IN_DIM * (IN_F32 ? 4 : 2);
    bool sv[CPT]; const char* sgp[CPT]; f16* slp[CPT];
    constexpr int LDSD = 16 * XP;          // f16 elems between xs buffers
#pragma unroll
    for (int k = 0; k < CPT; ++k) {
        const int cc = ltid + k * NT;
        sv[k] = (cc < NCH);
        const int r_ = (cc < NCH ? cc : 0) / EPR;
        const int o_ = (cc < NCH ? cc : 0) % EPR;
        sgp[k] = (const char*)xv + ((size_t)(bblk + r_) * IN_DIM + o_ * ELD) * (IN_F32 ? 4 : 2);
        slp[k] = &xs[0][r_][o_ * ELD];
    }

    // ---- output setup ----
    constexpr int OEPR = H / 4;            // u64 chunks per row; NT == 16*OEPR
    u64* opg = nullptr;
    f16* olds = nullptr;
    float* outp_f32 = nullptr;
    if constexpr (OUT_PANEL) {
        const int orow = ltid / OEPR, ooff = ltid % OEPR;
        opg  = (u64*)((f16*)outv + (size_t)(bblk + orow) * H) + ooff;
        olds = &hs[0][orow][ooff * 4];
    } else {
        outp_f32 = (float*)outv + ((size_t)bblk + 4 * q) * H + u;
    }
    constexpr int HLDSD = 16 * HP;

    // ---- pre-loop: zero h(0); wait upstream; stage x(0); issue x(1) ----
    for (int i = ltid; i < 16 * HP; i += NT) hs[0][i / HP][i % HP] = (f16)0.f;
    int seen = 0;
    if constexpr (!IN_F32) {
        do { seen = flag_load(in_flag); } while (seen < 1);
    }
#pragma unroll
    for (int k = 0; k < CPT; ++k) {
        if (sv[k]) {
            if constexpr (IN_F32) {
                const f32x4 v = *reinterpret_cast<const f32x4*>(sgp[k]);
                f16x4 h4;
                h4[0] = (f16)v[0]; h4[1] = (f16)v[1]; h4[2] = (f16)v[2]; h4[3] = (f16)v[3];
                *reinterpret_cast<f16x4*>(slp[k]) = h4;
            } else {
                u64 a = panel_load((const u64*)sgp[k]);
                u64 b = panel_load((const u64*)sgp[k] + 1);
                u64 pk[2] = {a, b};
                *reinterpret_cast<f16x8*>(slp[k]) = *reinterpret_cast<const f16x8*>(pk);
            }
            sgp[k] += XADVB;
        }
    }
    // issue x(1) into the ODD reg set (consumed at step 0's commit)
    f32x4 xr32O[CPT], xr32E[CPT];
    u64 xr16O[CPT][2], xr16E[CPT][2];
    if constexpr (!IN_F32) {
        if (seen < 2) { do { seen = flag_load(in_flag); } while (seen < 2); }
    }
#pragma unroll
    for (int k = 0; k < CPT; ++k) {
        if (sv[k]) {
            if constexpr (IN_F32) {
                xr32O[k] = *reinterpret_cast<const f32x4*>(sgp[k]);
            } else {
                xr16O[k][0] = panel_load((const u64*)sgp[k]);
                xr16O[k][1] = panel_load((const u64*)sgp[k] + 1);
            }
            sgp[k] += XADVB;
        }
    }
    barrier_lgkm();   // x(1) loads stay in flight across the barrier

    float hold[4] = {0.f, 0.f, 0.f, 0.f};

    // ---- one step; pbv/dodrain/dopub are literal at each call site.
    //      xcom* holds x(t+1) (loaded at t-1); xiss* receives x(t+2). ----
    auto step = [&](int t, int pbv, bool dodrain, bool dopub,
                    f32x4 (&c32)[CPT], f32x4 (&i32)[CPT],
                    u64 (&c16)[CPT][2], u64 (&i16)[CPT][2]) {
        if constexpr (OUT_PANEL) {
            if (dopub && t >= 4 && ltid == 0) flag_store(out_flag, t - 1);
        }

        // (1) write step t-1's output FIRST (h(t-1) sits in hs[pbv]) so the
        //     counted drain covers all stores without touching fresh loads
        if (t >= 1) {
            if constexpr (OUT_PANEL) {
                u64 v = *reinterpret_cast<const u64*>(olds + pbv * HLDSD);
                if constexpr (OUT_TANH) v = tanh4_f16(v);
                panel_store(opg, v);
                opg += (size_t)BATCH * H / 4;
            } else {
#pragma unroll
                for (int r = 0; r < 4; ++r) outp_f32[r * H] = hold[r];
                outp_f32 += (size_t)BATCH * H;
            }
        }

        // (2) issue prefetch of x(t+2)
        const bool iss = (t + 2 < T_STEPS);
        if (iss) {
            if constexpr (!IN_F32) {
                if (seen < t + 3) {
                    do { seen = flag_load(in_flag); } while (seen < t + 3);
                }
            }
#pragma unroll
            for (int k = 0; k < CPT; ++k) {
                if (sv[k]) {
                    if constexpr (IN_F32) {
                        i32[k] = *reinterpret_cast<const f32x4*>(sgp[k]);
                    } else {
                        i16[k][0] = panel_load((const u64*)sgp[k]);
                        i16[k][1] = panel_load((const u64*)sgp[k] + 1);
                    }
                    sgp[k] += XADVB;
                }
            }
        }

        // (3) A-fragments
        f16x8 a[KT];
#pragma unroll
        for (int kt = 0; kt < KTX; ++kt)
            a[kt] = *reinterpret_cast<const f16x8*>(&xs[pbv][col][kt * 32 + q * 8]);
#pragma unroll
        for (int kt = 0; kt < KTH; ++kt)
            a[KTX + kt] = *reinterpret_cast<const f16x8*>(&hs[pbv][col][kt * 32 + q * 8]);

        // MFMA (single accumulator chain, bias-seeded)
        f32x4 acc[4];
#pragma unroll
        for (int g = 0; g < 4; ++g)
            acc[g] = (f32x4){bias[g], bias[g], bias[g], bias[g]};
#pragma unroll
        for (int kt = 0; kt < KT; ++kt)
#pragma unroll
            for (int g = 0; g < 4; ++g)
                acc[g] = __builtin_amdgcn_mfma_f32_16x16x32_f16(a[kt], bw[g][kt], acc[g], 0, 0, 0);

        // gates (exp2 domain), merged-rcp forms:
        // si*tanh(g)*2L2E = 2L2E*(G-1)/((1+Ei)(G+1)),  h = (C-1)/((1+Eo)(C+1))
#pragma unroll
        for (int r = 0; r < 4; ++r) {
            const float yi = acc[0][r];
            const float yf = acc[1][r];
            const float yg = acc[2][r];   // scaled by 2*log2e
            const float yo = acc[3][r];
            const float Ei = exp2_f(-yi);
            const float G  = exp2_f(yg);                 // e^{2g}
            const float Ef = exp2_f(-yf);
            const float sf = rcp_f(1.0f + Ef);
            const float itg = (2.0f * L2E) * (G - 1.0f) *
                              rcp_f((1.0f + Ei) * (G + 1.0f));   // si * 2L2E*tanh(g)
            cst[r] = fmaf(sf, cst[r], itg);              // c' = 2*log2e*c
            const float C  = exp2_f(cst[r]);             // e^{2c'}
            const float Eo = exp2_f(-yo);
            const float h  = (C - 1.0f) * rcp_f((1.0f + Eo) * (C + 1.0f)); // so*tanh(c')
            hs[pbv ^ 1][4 * q + r][u] = (f16)h;
            if constexpr (!OUT_PANEL) hold[r] = h;
        }

        // (4) commit x(t+1) from regs loaded at step t-1 (no vm stall)
        const bool pf = (t + 1 < T_STEPS);
        if (pf) {
#pragma unroll
            for (int k = 0; k < CPT; ++k) {
                if (sv[k]) {
                    f16* dst = slp[k] + (pbv ^ 1) * LDSD;
                    if constexpr (IN_F32) {
                        f16x4 h4;
                        h4[0] = (f16)c32[k][0]; h4[1] = (f16)c32[k][1];
                        h4[2] = (f16)c32[k][2]; h4[3] = (f16)c32[k][3];
                        *reinterpret_cast<f16x4*>(dst) = h4;
                    } else {
                        *reinterpret_cast<f16x8*>(dst) =
                            *reinterpret_cast<const f16x8*>(c16[k]);
                    }
                }
            }
        }

        // (5) refresh 'seen' only on publish-cadence steps
        if constexpr (!IN_F32) {
            if (dopub && seen < t + 9) seen = flag_load(in_flag);
        }

        if (dodrain) barrier_drain_k<NLOAD>(); else barrier_lgkm();
    };

    for (int tb = 0; tb < T_STEPS; tb += 4) {
        // t even: commit x(t+1) [odd set], issue x(t+2) [even set]; t odd: swap
        step(tb + 0, 0, false, true,  xr32O, xr32E, xr16O, xr16E);
        step(tb + 1, 1, false, false, xr32E, xr32O, xr16E, xr16O);
        step(tb + 2, 0, false, false, xr32O, xr32E, xr16O, xr16E);
        step(tb + 3, 1, true,  false, xr32E, xr32O, xr16E, xr16O);
    }

    // ---- epilogue: final output (h(T-1) in hs[0]), full drain, final flag ----
    if constexpr (OUT_PANEL) {
        u64 v = *reinterpret_cast<const u64*>(olds);
        if constexpr (OUT_TANH) v = tanh4_f16(v);
        panel_store(opg, v);
    } else {
#pragma unroll
        for (int r = 0; r < 4; ++r) outp_f32[r * H] = hold[r];
    }
    barrier_drain();
    if constexpr (OUT_PANEL) {
        if (ltid == 0) flag_store(out_flag, T_STEPS + 4);
    }
}

__global__ __launch_bounds__(512, 1)
void lstm_fused(const float* __restrict__ X,
                const float* __restrict__ w1_ih, const float* __restrict__ w1_hh,
                const float* __restrict__ b1_ih, const float* __restrict__ b1_hh,
                const float* __restrict__ w2_ih, const float* __restrict__ w2_hh,
                const float* __restrict__ b2_ih, const float* __restrict__ b2_hh,
                const float* __restrict__ w3_ih, const float* __restrict__ w3_hh,
                const float* __restrict__ b3_ih, const float* __restrict__ b3_hh,
                const float* __restrict__ w4_ih, const float* __restrict__ w4_hh,
                const float* __restrict__ b4_ih, const float* __restrict__ b4_hh,
                f16* __restrict__ h1, f16* __restrict__ h2, f16* __restrict__ h3,
                int* __restrict__ flags, float* __restrict__ out)
{
    __shared__ __attribute__((aligned(16))) char smem[45056];
    const int b = blockIdx.x, tid = threadIdx.x;

    if (b < 16) {
        // L1: 64 -> 128, fp32 in, panel out, 1 group/block (512 thr)
        lstm_layer_dev<64, 128, true, true, false>(
            smem, X, nullptr, flags + 0 * 16 + b,
            w1_ih, w1_hh, b1_ih, b1_hh, h1, b, tid);
    } else if (b < 20) {
        // L2: 128 -> 32, 4 groups/block (128 thr each); bottleneck tanh is
        // applied on the PANEL path only (recurrence h stays raw)
        const int gl = tid >> 7;
        const int g  = (b - 16) * 4 + gl;
        lstm_layer_dev<128, 32, false, true, true>(
            smem + gl * 11264, h1, flags + 0 * 16 + g, flags + 1 * 16 + g,
            w2_ih, w2_hh, b2_ih, b2_hh, h2, g, tid & 127);
    } else if (b < 36) {
        // L3: 32 -> 128; input panel h2 is already tanh'd
        const int g = b - 20;
        lstm_layer_dev<32, 128, false, true, false>(
            smem, h2, flags + 1 * 16 + g, flags + 2 * 16 + g,
            w3_ih, w3_hh, b3_ih, b3_hh, h3, g, tid);
    } else {
        // L4: 128 -> 64, 2 groups/block (256 thr each), fp32 final out
        const int gl = tid >> 8;
        const int g  = (b - 36) * 2 + gl;
        lstm_layer_dev<128, 64, false, false, false>(
            smem + gl * 13312, h3, flags + 2 * 16 + g, nullptr,
            w4_ih, w4_hh, b4_ih, b4_hh, out, g, tid & 255);
    }
}

extern "C" void kernel_launch(void* const* d_in, const int* in_sizes, int n_in,
                              void* d_out, int out_size, void* d_ws, size_t ws_size,
                              hipStream_t stream) {
    const float* X     = (const float*)d_in[0];
    const float* w1_ih = (const float*)d_in[1];
    const float* w1_hh = (const float*)d_in[2];
    const float* b1_ih = (const float*)d_in[3];
    const float* b1_hh = (const float*)d_in[4];
    const float* w2_ih = (const float*)d_in[5];
    const float* w2_hh = (const float*)d_in[6];
    const float* b2_ih = (const float*)d_in[7];
    const float* b2_hh = (const float*)d_in[8];
    const float* w3_ih = (const float*)d_in[9];
    const float* w3_hh = (const float*)d_in[10];
    const float* b3_ih = (const float*)d_in[11];
    const float* b3_hh = (const float*)d_in[12];
    const float* w4_ih = (const float*)d_in[13];
    const float* w4_hh = (const float*)d_in[14];
    const float* b4_ih = (const float*)d_in[15];
    const float* b4_hh = (const float*)d_in[16];

    float* out = (float*)d_out;

    // ws: flags[48] ints (poison 0xAAAAAAAA < 0 => "not ready"), then f16
    // panels h1 [T,B,128], h2 [T,B,32], h3 [T,B,128]
    int* flags = (int*)d_ws;
    f16* h1 = (f16*)((char*)d_ws + 256);
    f16* h2 = h1 + (size_t)T_STEPS * BATCH * 128;
    f16* h3 = h2 + (size_t)T_STEPS * BATCH * 32;

    lstm_fused<<<44, 512, 0, stream>>>(X,
        w1_ih, w1_hh, b1_ih, b1_hh, w2_ih, w2_hh, b2_ih, b2_hh,
        w3_ih, w3_hh, b3_ih, b3_hh, w4_ih, w4_hh, b4_ih, b4_hh,
        h1, h2, h3, flags, out);
}